// Round 3
// baseline (835.146 us; speedup 1.0000x reference)
//
#include <hip/hip_runtime.h>
#include <cstdint>
#include <cstddef>

typedef __attribute__((ext_vector_type(8))) short bf16x8;   // MFMA A/B frag (4 VGPRs)
typedef __attribute__((ext_vector_type(16))) float f32x16;  // MFMA C/D (16 VGPRs)

__device__ __forceinline__ unsigned short f2bf(float f) {   // fp32 -> bf16 RNE
    unsigned int u = __builtin_bit_cast(unsigned int, f);
    u += 0x7fffu + ((u >> 16) & 1u);
    return (unsigned short)(u >> 16);
}

// packed fp32x2 -> bf16x2 (HW v_cvt_pk_bf16_f32 on gfx950 when available)
__device__ __forceinline__ unsigned int pk2(float a, float b) {
#if __has_builtin(__builtin_amdgcn_cvt_pk_bf16_f32)
    auto r = __builtin_amdgcn_cvt_pk_bf16_f32(a, b);
    return __builtin_bit_cast(unsigned int, r);
#else
    return (unsigned int)f2bf(a) | ((unsigned int)f2bf(b) << 16);
#endif
}

template<int CTRL>
__device__ __forceinline__ float dpp_add(float v) {
    int t = __builtin_amdgcn_update_dpp(0, __builtin_bit_cast(int, v), CTRL, 0xf, 0xf, true);
    return v + __builtin_bit_cast(float, t);
}
// row_shr:1=0x111 :2=0x112 :4=0x114 :8=0x118 ; row_bcast15=0x142 ; row_ror:8=0x128

__device__ __forceinline__ float fast_tanh(float x) {
    float e = __expf(2.0f * x);
    return 1.0f - 2.0f / (e + 1.0f);
}

// ---------------- prep: W1t[128][128], W2t[128][208] bf16, [n][k] ----------------
// W2t k-layout: k' 0..99 = W2 rows 0..99 (x), 100..103 = 0, 104..203 = W2 rows
// 100..199 (msg), 204..207 = 0  -> 13 frag-blocks of 16 with a clean hi-half split.
__global__ void prep_kernel(const float* __restrict__ W1, const float* __restrict__ W2,
                            unsigned short* __restrict__ W1t, unsigned short* __restrict__ W2t)
{
    int idx = blockIdx.x * 256 + threadIdx.x;
    if (idx < 128 * 128) {
        int nn = idx >> 7, kk = idx & 127;
        W1t[idx] = (nn < 100 && kk < 100) ? f2bf(W1[kk * 100 + nn]) : (unsigned short)0;
    } else {
        int j = idx - 128 * 128;
        if (j < 128 * 208) {
            int nn = j / 208, kk = j - nn * 208;
            unsigned short v = 0;
            if (nn < 100) {
                if (kk < 100) v = f2bf(W2[kk * 100 + nn]);
                else if (kk >= 104 && kk < 204) v = f2bf(W2[(kk - 4) * 100 + nn]);
            }
            W2t[j] = v;
        }
    }
}

// ---------------- fused kernel: attention (32 nodes) + 2-layer MLP ----------------
#define HP 104   // h_s / msg_s pitch (ushorts); 100 real + 4 zero pad
#define P2P 104  // part2 pitch (floats)

__global__ __launch_bounds__(256, 5) void fused_kernel(
    const int* __restrict__ nodes, const int* __restrict__ nei,
    const float* __restrict__ wei, const float* __restrict__ s_vec,
    const float* __restrict__ emb, const float* __restrict__ W1,
    const float* __restrict__ b1, const float* __restrict__ q1,
    const unsigned short* __restrict__ W1t, const unsigned short* __restrict__ W2t,
    const float* __restrict__ b2, float* __restrict__ out, int N)
{
    // h_s: neighbor rows [32][104] bf16 (attn) -> x rows (layer)
    // hst: hs=h*s, k-block-tiled [14 blocks][32 rows][8 ushorts] (conflict-free b128)
    // msg_s: per-node attention messages, bf16, persists into the layer phase
    __shared__ __align__(16) unsigned short h_s[32 * HP];     // 6656 B
    __shared__ __align__(16) unsigned short hst[14 * 32 * 8]; // 7168 B
    __shared__ __align__(16) unsigned short msg_s[32 * HP];   // 6656 B
    __shared__ __align__(16) float part2[16 * P2P];           // 6656 B
    __shared__ __align__(16) float spart[4 * 32];             // 512 B
    __shared__ __align__(16) float wei_s[32];                 // 128 B

    const int tid  = threadIdx.x;
    const int lane = tid & 63;
    const int w    = tid >> 6;
    const int col  = lane & 31;
    const int hi   = lane >> 5;
    const int n    = w * 32 + col;          // output column 0..127 (>=100 masked)
    const int n0   = blockIdx.x * 32;       // this block's 32 consecutive nodes

    // persistent W1 fragments + per-column constants
    bf16x8 Bf1[7];
    #pragma unroll
    for (int ks = 0; ks < 7; ++ks)
        Bf1[ks] = *(const bf16x8*)(W1t + n * 128 + ks * 16 + hi * 8);
    const bool nok   = (n < 100);
    const float b1v  = nok ? b1[n] : 0.0f;
    const float w100 = nok ? W1[100 * 100 + n] : 0.0f;  // W1 row 100 = wei column
    const float q1v  = nok ? q1[n] : 0.0f;

    // zero pads once: hst k>=100 (block 12 hi-half + block 13), h_s/msg_s d 100..103
    if (tid < 32) {
        *(uint2*)&hst[(12 * 32 + tid) * 8 + 4] = make_uint2(0, 0);
        *(uint4*)&hst[(13 * 32 + tid) * 8]     = make_uint4(0, 0, 0, 0);
        *(uint2*)&h_s[tid * HP + 100]          = make_uint2(0, 0);
        *(uint2*)&msg_s[tid * HP + 100]        = make_uint2(0, 0);
    }
    __syncthreads();

    const int gk = tid >> 3;   // staging row 0..31
    const int gj = tid & 7;    // staging float4-lane 0..7

    // software prefetch of nei/wei one node ahead (breaks nei->gather chain)
    int   nidx_nx = 0;
    float wv_nx   = 0.0f;
    if (n0 < N) {
        nidx_nx = nei[(size_t)n0 * 32 + gk];
        if (tid < 32) wv_nx = wei[(size_t)n0 * 32 + tid];
    }

    for (int it = 0; it < 32; ++it) {
        const int node = n0 + it;
        if (node >= N) break;              // block-uniform
        const int   nidx = nidx_nx;
        const float wv   = wv_nx;
        if (it + 1 < 32 && node + 1 < N) {
            nidx_nx = nei[(size_t)(node + 1) * 32 + gk];
            if (tid < 32) wv_nx = wei[(size_t)(node + 1) * 32 + tid];
        }

        // ---- stage: gather neighbor row -> h_s (bf16) + hst (bf16, tiled, *s)
        {
            if (tid < 32) wei_s[tid] = wv;
            const float4* erow = (const float4*)(emb + (size_t)nidx * 100);
            const float4* srow = (const float4*)(s_vec + (size_t)node * 100);
            float4 h0 = erow[gj],      s0 = srow[gj];
            float4 h1 = erow[gj + 8],  s1 = srow[gj + 8];
            float4 h2 = erow[gj + 16], s2 = srow[gj + 16];
            float4 h3, s3;
            const bool t24 = (gj == 0);
            if (t24) { h3 = erow[24]; s3 = srow[24]; }
            #define ST_C4(c4, h4, s4) { \
                *(uint2*)&h_s[gk * HP + (c4) * 4] = \
                    make_uint2(pk2(h4.x, h4.y), pk2(h4.z, h4.w)); \
                *(uint2*)&hst[(((c4) >> 1) * 32 + gk) * 8 + ((c4) & 1) * 4] = \
                    make_uint2(pk2(h4.x * s4.x, h4.y * s4.y), pk2(h4.z * s4.z, h4.w * s4.w)); }
            ST_C4(gj,      h0, s0)
            ST_C4(gj + 8,  h1, s1)
            ST_C4(gj + 16, h2, s2)
            if (t24) { ST_C4(24, h3, s3) }
            #undef ST_C4
        }
        __syncthreads();   // B1

        // ---- score matmul: acc init (bias + wei*W1row100) + 7 MFMA k-steps
        f32x16 acc;
        #pragma unroll
        for (int q = 0; q < 4; ++q) {
            float4 wq = *(const float4*)&wei_s[q * 8 + hi * 4];
            acc[q * 4 + 0] = fmaf(wq.x, w100, b1v);
            acc[q * 4 + 1] = fmaf(wq.y, w100, b1v);
            acc[q * 4 + 2] = fmaf(wq.z, w100, b1v);
            acc[q * 4 + 3] = fmaf(wq.w, w100, b1v);
        }
        #pragma unroll
        for (int ks = 0; ks < 7; ++ks) {
            bf16x8 a = *(const bf16x8*)&hst[((2 * ks + hi) * 32 + col) * 8];
            acc = __builtin_amdgcn_mfma_f32_32x32x16_bf16(a, Bf1[ks], acc, 0, 0, 0);
        }

        // ---- epilogue: per-row sum_n tanh(S)*q1 via DPP, publish to spart
        float sv[16];
        #pragma unroll
        for (int r = 0; r < 16; ++r) sv[r] = fast_tanh(acc[r]) * q1v;
        #pragma unroll
        for (int r = 0; r < 16; ++r) {
            float v = sv[r];
            v = dpp_add<0x111>(v);
            v = dpp_add<0x112>(v);
            v = dpp_add<0x114>(v);
            v = dpp_add<0x118>(v);
            v = dpp_add<0x142>(v);   // lane31 = sum(0..31), lane63 = sum(32..63)
            sv[r] = v;
        }
        if (col == 31) {
            #pragma unroll
            for (int q = 0; q < 4; ++q)
                *(float4*)&spart[w * 32 + q * 8 + hi * 4] =
                    make_float4(sv[q * 4], sv[q * 4 + 1], sv[q * 4 + 2], sv[q * 4 + 3]);
        }
        __syncthreads();   // B2

        // ---- softmax, redundantly per wave (no extra barrier); att via bpermute
        float attk;
        {
            float s = spart[col] + spart[32 + col] + spart[64 + col] + spart[96 + col];
            float mx = s;
            #pragma unroll
            for (int off = 16; off; off >>= 1) mx = fmaxf(mx, __shfl_xor(mx, off));
            float e = __expf(s - mx);
            float den = e;
            #pragma unroll
            for (int off = 16; off; off >>= 1) den += __shfl_xor(den, off);
            float attv = e / den;
            attk = __shfl(attv, w * 8 + (lane >> 3));   // att for my k-row
        }

        // ---- msg partials: wave w owns k in [8w,8w+8); lane: k=8w+(L>>3), oct=L&7
        {
            const int oct  = lane & 7;
            const int krow = w * 8 + (lane >> 3);
            const float a  = attk;
            uint4 r1 = *(const uint4*)&h_s[krow * HP + oct * 8];
            const int oct2 = (oct < 5) ? oct : 4;   // clamped dup, masked at write
            uint4 r2 = *(const uint4*)&h_s[krow * HP + 64 + oct2 * 8];
            float m1[8], m2[8];
            #define UNP2(u, d0, d1) { d0 = __builtin_bit_cast(float, (u) << 16); \
                                      d1 = __builtin_bit_cast(float, (u) & 0xffff0000u); }
            { float t0,t1; UNP2(r1.x,t0,t1); m1[0]=a*t0; m1[1]=a*t1; }
            { float t0,t1; UNP2(r1.y,t0,t1); m1[2]=a*t0; m1[3]=a*t1; }
            { float t0,t1; UNP2(r1.z,t0,t1); m1[4]=a*t0; m1[5]=a*t1; }
            { float t0,t1; UNP2(r1.w,t0,t1); m1[6]=a*t0; m1[7]=a*t1; }
            { float t0,t1; UNP2(r2.x,t0,t1); m2[0]=a*t0; m2[1]=a*t1; }
            { float t0,t1; UNP2(r2.y,t0,t1); m2[2]=a*t0; m2[3]=a*t1; }
            { float t0,t1; UNP2(r2.z,t0,t1); m2[4]=a*t0; m2[5]=a*t1; }
            { float t0,t1; UNP2(r2.w,t0,t1); m2[6]=a*t0; m2[7]=a*t1; }
            #undef UNP2
            #pragma unroll
            for (int j = 0; j < 8; ++j) {   // row_ror:8 pairs k and k^1
                m1[j] = dpp_add<0x128>(m1[j]);
                m2[j] = dpp_add<0x128>(m2[j]);
            }
            if ((lane & 8) == 0) {
                const int slot = w * 4 + (lane >> 4);
                float* p = &part2[slot * P2P];
                *(float4*)&p[oct * 8]     = make_float4(m1[0], m1[1], m1[2], m1[3]);
                *(float4*)&p[oct * 8 + 4] = make_float4(m1[4], m1[5], m1[6], m1[7]);
                if (oct < 5) {
                    *(float4*)&p[64 + oct * 8]     = make_float4(m2[0], m2[1], m2[2], m2[3]);
                    *(float4*)&p[64 + oct * 8 + 4] = make_float4(m2[4], m2[5], m2[6], m2[7]);
                }
            }
        }
        __syncthreads();   // B4

        // ---- reduce 16 k-pair partials -> msg_s row (bf16), waves 0,1
        if (w < 2) {
            int d = w * 64 + lane;
            if (d < 100) {
                float s = 0.0f;
                #pragma unroll
                for (int sl = 0; sl < 16; ++sl) s += part2[sl * P2P + d];
                msg_s[it * HP + d] = f2bf(s);
            }
        }
    }

    // ================= layer phase: x = relu([x,msg]@W2+b2) twice =================
    __syncthreads();   // all attn reads of h_s done; msg_s rows final after B_L1

    // W2 fragments + x-gather (emb[nodes]) -> h_s region
    bf16x8 Bf2[13];
    #pragma unroll
    for (int ks = 0; ks < 13; ++ks)
        Bf2[ks] = *(const bf16x8*)(W2t + n * 208 + ks * 16 + hi * 8);
    const float b2v = nok ? b2[n] : 0.0f;
    {
        int row = n0 + gk;
        int rc = row < N ? row : N - 1;
        const float4* xr = (const float4*)(emb + (size_t)nodes[rc] * 100);
        float4 x0 = xr[gj], x1 = xr[gj + 8], x2 = xr[gj + 16];
        float4 x3; const bool t24 = (gj == 0);
        if (t24) x3 = xr[24];
        *(uint2*)&h_s[gk * HP + gj * 4]        = make_uint2(pk2(x0.x, x0.y), pk2(x0.z, x0.w));
        *(uint2*)&h_s[gk * HP + (gj + 8) * 4]  = make_uint2(pk2(x1.x, x1.y), pk2(x1.z, x1.w));
        *(uint2*)&h_s[gk * HP + (gj + 16) * 4] = make_uint2(pk2(x2.x, x2.y), pk2(x2.z, x2.w));
        if (t24)
            *(uint2*)&h_s[gk * HP + 96]        = make_uint2(pk2(x3.x, x3.y), pk2(x3.z, x3.w));
    }
    __syncthreads();   // B_L1

    // A-frag address: k' blocks 0..12 -> h_s, 13..25 -> msg_s (ks=6 splits on hi)
    #define AFRAG(ks) (*(const bf16x8*)( \
        (ks) < 6  ? &h_s[col * HP + (ks) * 16 + hi * 8] : \
        (ks) == 6 ? (hi ? &msg_s[col * HP] : &h_s[col * HP + 96]) : \
                    &msg_s[col * HP + (ks) * 16 + hi * 8 - 104]))

    f32x16 acc;
    #pragma unroll
    for (int r = 0; r < 16; ++r) acc[r] = b2v;
    #pragma unroll
    for (int ks = 0; ks < 13; ++ks)
        acc = __builtin_amdgcn_mfma_f32_32x32x16_bf16(AFRAG(ks), Bf2[ks], acc, 0, 0, 0);
    __syncthreads();   // B_L2: pass-1 reads done
    if (nok) {
        #pragma unroll
        for (int r = 0; r < 16; ++r) {
            int m = (r & 3) + 8 * (r >> 2) + 4 * hi;
            h_s[m * HP + n] = f2bf(fmaxf(acc[r], 0.0f));
        }
    }
    __syncthreads();   // B_L3

    f32x16 acc2;
    #pragma unroll
    for (int r = 0; r < 16; ++r) acc2[r] = b2v;
    #pragma unroll
    for (int ks = 0; ks < 13; ++ks)
        acc2 = __builtin_amdgcn_mfma_f32_32x32x16_bf16(AFRAG(ks), Bf2[ks], acc2, 0, 0, 0);
    #undef AFRAG
    if (nok) {
        #pragma unroll
        for (int r = 0; r < 16; ++r) {
            int m = (r & 3) + 8 * (r >> 2) + 4 * hi;
            int row = n0 + m;
            if (row < N) out[(size_t)row * 100 + n] = fmaxf(acc2[r], 0.0f);
        }
    }
}

// ---------------- launch ----------------
extern "C" void kernel_launch(void* const* d_in, const int* in_sizes, int n_in,
                              void* d_out, int out_size, void* d_ws, size_t ws_size,
                              hipStream_t stream) {
    const int*   nodes = (const int*)d_in[0];
    const int*   nei   = (const int*)d_in[1];
    const float* wei   = (const float*)d_in[2];
    const float* s_vec = (const float*)d_in[3];
    const float* emb   = (const float*)d_in[4];
    const float* W1    = (const float*)d_in[5];
    const float* b1    = (const float*)d_in[6];
    const float* q1    = (const float*)d_in[7];
    const float* W2    = (const float*)d_in[8];
    const float* b2    = (const float*)d_in[9];
    float* out = (float*)d_out;
    const int N = in_sizes[0];

    unsigned short* W1t = (unsigned short*)d_ws;       // 128*128*2 = 32 KB
    unsigned short* W2t = W1t + 128 * 128;             // 128*208*2 = 52 KB

    prep_kernel<<<168, 256, 0, stream>>>(W1, W2, W1t, W2t);
    const int gB = (N + 31) / 32;
    fused_kernel<<<gB, 256, 0, stream>>>(nodes, nei, wei, s_vec, emb, W1, b1, q1,
                                         W1t, W2t, b2, out, N);
}

// Round 4
// 675.800 us; speedup vs baseline: 1.2358x; 1.2358x over previous
//
#include <hip/hip_runtime.h>
#include <cstdint>
#include <cstddef>

typedef __attribute__((ext_vector_type(8))) short bf16x8;   // MFMA A/B frag (4 VGPRs)
typedef __attribute__((ext_vector_type(16))) float f32x16;  // MFMA C/D (16 VGPRs)

__device__ __forceinline__ unsigned short f2bf(float f) {   // fp32 -> bf16 RNE
    unsigned int u = __builtin_bit_cast(unsigned int, f);
    u += 0x7fffu + ((u >> 16) & 1u);
    return (unsigned short)(u >> 16);
}

// packed fp32x2 -> bf16x2 (HW v_cvt_pk_bf16_f32 on gfx950 when available)
__device__ __forceinline__ unsigned int pk2(float a, float b) {
#if __has_builtin(__builtin_amdgcn_cvt_pk_bf16_f32)
    auto r = __builtin_amdgcn_cvt_pk_bf16_f32(a, b);
    return __builtin_bit_cast(unsigned int, r);
#else
    return (unsigned int)f2bf(a) | ((unsigned int)f2bf(b) << 16);
#endif
}

template<int CTRL>
__device__ __forceinline__ float dpp_add(float v) {
    int t = __builtin_amdgcn_update_dpp(0, __builtin_bit_cast(int, v), CTRL, 0xf, 0xf, true);
    return v + __builtin_bit_cast(float, t);
}
// row_shr:1=0x111 :2=0x112 :4=0x114 :8=0x118 ; row_bcast15=0x142 ; row_ror:8=0x128

__device__ __forceinline__ float fast_tanh(float x) {
    float e = __expf(2.0f * x);
    return 1.0f - 2.0f / (e + 1.0f);
}

// ---------------- prep: W1t[128][128], W2t[128][208] bf16, [n][k] ----------------
// W2t k-layout: k' 0..99 = W2 rows 0..99 (x), 100..103 = 0, 104..203 = W2 rows
// 100..199 (msg), 204..207 = 0  -> 13 frag-blocks of 16 with a clean hi-half split.
__global__ void prep_kernel(const float* __restrict__ W1, const float* __restrict__ W2,
                            unsigned short* __restrict__ W1t, unsigned short* __restrict__ W2t)
{
    int idx = blockIdx.x * 256 + threadIdx.x;
    if (idx < 128 * 128) {
        int nn = idx >> 7, kk = idx & 127;
        W1t[idx] = (nn < 100 && kk < 100) ? f2bf(W1[kk * 100 + nn]) : (unsigned short)0;
    } else {
        int j = idx - 128 * 128;
        if (j < 128 * 208) {
            int nn = j / 208, kk = j - nn * 208;
            unsigned short v = 0;
            if (nn < 100) {
                if (kk < 100) v = f2bf(W2[kk * 100 + nn]);
                else if (kk >= 104 && kk < 204) v = f2bf(W2[(kk - 4) * 100 + nn]);
            }
            W2t[j] = v;
        }
    }
}

// ---------------- fused kernel: attention (32 nodes) + 2-layer MLP ----------------
// NOTE: no min-waves arg in __launch_bounds__ — round 3 used (256,5), which caps
// the unified VGPR+AGPR budget at ~96 regs -> massive scratch spill (VGPR_Count 48,
// WRITE_SIZE 20->102 MB, FETCH 0.41->1.26 GB). LDS (28.2 KB) bounds occupancy at
// 5 blocks/CU anyway; let the allocator take the registers it needs.
#define HP 104   // h_s / msg_s pitch (ushorts); 100 real + 4 zero pad
#define P2P 104  // part2 pitch (floats)

__global__ __launch_bounds__(256) void fused_kernel(
    const int* __restrict__ nodes, const int* __restrict__ nei,
    const float* __restrict__ wei, const float* __restrict__ s_vec,
    const float* __restrict__ emb, const float* __restrict__ W1,
    const float* __restrict__ b1, const float* __restrict__ q1,
    const unsigned short* __restrict__ W1t, const unsigned short* __restrict__ W2t,
    const float* __restrict__ b2, float* __restrict__ out, int N)
{
    // h_s: neighbor rows [32][104] bf16 (attn) -> x rows (layer)
    // hst: hs=h*s, k-block-tiled [14 blocks][32 rows][8 ushorts] (conflict-free b128)
    // msg_s: per-node attention messages, bf16, persists into the layer phase
    __shared__ __align__(16) unsigned short h_s[32 * HP];     // 6656 B
    __shared__ __align__(16) unsigned short hst[14 * 32 * 8]; // 7168 B
    __shared__ __align__(16) unsigned short msg_s[32 * HP];   // 6656 B
    __shared__ __align__(16) float part2[16 * P2P];           // 6656 B
    __shared__ __align__(16) float spart[4 * 32];             // 512 B
    __shared__ __align__(16) float wei_s[32];                 // 128 B

    const int tid  = threadIdx.x;
    const int lane = tid & 63;
    const int w    = tid >> 6;
    const int col  = lane & 31;
    const int hi   = lane >> 5;
    const int n    = w * 32 + col;          // output column 0..127 (>=100 masked)
    const int n0   = blockIdx.x * 32;       // this block's 32 consecutive nodes

    // persistent W1 fragments + per-column constants
    bf16x8 Bf1[7];
    #pragma unroll
    for (int ks = 0; ks < 7; ++ks)
        Bf1[ks] = *(const bf16x8*)(W1t + n * 128 + ks * 16 + hi * 8);
    const bool nok   = (n < 100);
    const float b1v  = nok ? b1[n] : 0.0f;
    const float w100 = nok ? W1[100 * 100 + n] : 0.0f;  // W1 row 100 = wei column
    const float q1v  = nok ? q1[n] : 0.0f;

    // zero pads once: hst k>=100 (block 12 hi-half + block 13), h_s/msg_s d 100..103
    if (tid < 32) {
        *(uint2*)&hst[(12 * 32 + tid) * 8 + 4] = make_uint2(0, 0);
        *(uint4*)&hst[(13 * 32 + tid) * 8]     = make_uint4(0, 0, 0, 0);
        *(uint2*)&h_s[tid * HP + 100]          = make_uint2(0, 0);
        *(uint2*)&msg_s[tid * HP + 100]        = make_uint2(0, 0);
    }
    __syncthreads();

    const int gk = tid >> 3;   // staging row 0..31
    const int gj = tid & 7;    // staging float4-lane 0..7

    // software prefetch of nei/wei one node ahead (breaks nei->gather chain)
    int   nidx_nx = 0;
    float wv_nx   = 0.0f;
    if (n0 < N) {
        nidx_nx = nei[(size_t)n0 * 32 + gk];
        if (tid < 32) wv_nx = wei[(size_t)n0 * 32 + tid];
    }

    for (int it = 0; it < 32; ++it) {
        const int node = n0 + it;
        if (node >= N) break;              // block-uniform
        const int   nidx = nidx_nx;
        const float wv   = wv_nx;
        if (it + 1 < 32 && node + 1 < N) {
            nidx_nx = nei[(size_t)(node + 1) * 32 + gk];
            if (tid < 32) wv_nx = wei[(size_t)(node + 1) * 32 + tid];
        }

        // ---- stage: gather neighbor row -> h_s (bf16) + hst (bf16, tiled, *s)
        {
            if (tid < 32) wei_s[tid] = wv;
            const float4* erow = (const float4*)(emb + (size_t)nidx * 100);
            const float4* srow = (const float4*)(s_vec + (size_t)node * 100);
            float4 h0 = erow[gj],      s0 = srow[gj];
            float4 h1 = erow[gj + 8],  s1 = srow[gj + 8];
            float4 h2 = erow[gj + 16], s2 = srow[gj + 16];
            float4 h3, s3;
            const bool t24 = (gj == 0);
            if (t24) { h3 = erow[24]; s3 = srow[24]; }
            #define ST_C4(c4, h4, s4) { \
                *(uint2*)&h_s[gk * HP + (c4) * 4] = \
                    make_uint2(pk2(h4.x, h4.y), pk2(h4.z, h4.w)); \
                *(uint2*)&hst[(((c4) >> 1) * 32 + gk) * 8 + ((c4) & 1) * 4] = \
                    make_uint2(pk2(h4.x * s4.x, h4.y * s4.y), pk2(h4.z * s4.z, h4.w * s4.w)); }
            ST_C4(gj,      h0, s0)
            ST_C4(gj + 8,  h1, s1)
            ST_C4(gj + 16, h2, s2)
            if (t24) { ST_C4(24, h3, s3) }
            #undef ST_C4
        }
        __syncthreads();   // B1

        // ---- score matmul: acc init (bias + wei*W1row100) + 7 MFMA k-steps
        f32x16 acc;
        #pragma unroll
        for (int q = 0; q < 4; ++q) {
            float4 wq = *(const float4*)&wei_s[q * 8 + hi * 4];
            acc[q * 4 + 0] = fmaf(wq.x, w100, b1v);
            acc[q * 4 + 1] = fmaf(wq.y, w100, b1v);
            acc[q * 4 + 2] = fmaf(wq.z, w100, b1v);
            acc[q * 4 + 3] = fmaf(wq.w, w100, b1v);
        }
        #pragma unroll
        for (int ks = 0; ks < 7; ++ks) {
            bf16x8 a = *(const bf16x8*)&hst[((2 * ks + hi) * 32 + col) * 8];
            acc = __builtin_amdgcn_mfma_f32_32x32x16_bf16(a, Bf1[ks], acc, 0, 0, 0);
        }

        // ---- epilogue: per-row sum_n tanh(S)*q1 via DPP, publish to spart
        float sv[16];
        #pragma unroll
        for (int r = 0; r < 16; ++r) sv[r] = fast_tanh(acc[r]) * q1v;
        #pragma unroll
        for (int r = 0; r < 16; ++r) {
            float v = sv[r];
            v = dpp_add<0x111>(v);
            v = dpp_add<0x112>(v);
            v = dpp_add<0x114>(v);
            v = dpp_add<0x118>(v);
            v = dpp_add<0x142>(v);   // lane31 = sum(0..31), lane63 = sum(32..63)
            sv[r] = v;
        }
        if (col == 31) {
            #pragma unroll
            for (int q = 0; q < 4; ++q)
                *(float4*)&spart[w * 32 + q * 8 + hi * 4] =
                    make_float4(sv[q * 4], sv[q * 4 + 1], sv[q * 4 + 2], sv[q * 4 + 3]);
        }
        __syncthreads();   // B2

        // ---- softmax, redundantly per wave (no extra barrier)
        float attk;
        {
            float s = spart[col] + spart[32 + col] + spart[64 + col] + spart[96 + col];
            float mx = s;
            #pragma unroll
            for (int off = 16; off; off >>= 1) mx = fmaxf(mx, __shfl_xor(mx, off));
            float e = __expf(s - mx);
            float den = e;
            #pragma unroll
            for (int off = 16; off; off >>= 1) den += __shfl_xor(den, off);
            float attv = e / den;
            attk = __shfl(attv, w * 8 + (lane >> 3));   // att for my k-row
        }

        // ---- msg partials: wave w owns k in [8w,8w+8); lane: k=8w+(L>>3), oct=L&7
        {
            const int oct  = lane & 7;
            const int krow = w * 8 + (lane >> 3);
            const float a  = attk;
            uint4 r1 = *(const uint4*)&h_s[krow * HP + oct * 8];
            const int oct2 = (oct < 5) ? oct : 4;   // clamped dup, masked at write
            uint4 r2 = *(const uint4*)&h_s[krow * HP + 64 + oct2 * 8];
            float m1[8], m2[8];
            #define UNP2(u, d0, d1) { d0 = __builtin_bit_cast(float, (u) << 16); \
                                      d1 = __builtin_bit_cast(float, (u) & 0xffff0000u); }
            { float t0,t1; UNP2(r1.x,t0,t1); m1[0]=a*t0; m1[1]=a*t1; }
            { float t0,t1; UNP2(r1.y,t0,t1); m1[2]=a*t0; m1[3]=a*t1; }
            { float t0,t1; UNP2(r1.z,t0,t1); m1[4]=a*t0; m1[5]=a*t1; }
            { float t0,t1; UNP2(r1.w,t0,t1); m1[6]=a*t0; m1[7]=a*t1; }
            { float t0,t1; UNP2(r2.x,t0,t1); m2[0]=a*t0; m2[1]=a*t1; }
            { float t0,t1; UNP2(r2.y,t0,t1); m2[2]=a*t0; m2[3]=a*t1; }
            { float t0,t1; UNP2(r2.z,t0,t1); m2[4]=a*t0; m2[5]=a*t1; }
            { float t0,t1; UNP2(r2.w,t0,t1); m2[6]=a*t0; m2[7]=a*t1; }
            #undef UNP2
            #pragma unroll
            for (int j = 0; j < 8; ++j) {   // row_ror:8 pairs k and k^1
                m1[j] = dpp_add<0x128>(m1[j]);
                m2[j] = dpp_add<0x128>(m2[j]);
            }
            if ((lane & 8) == 0) {
                const int slot = w * 4 + (lane >> 4);
                float* p = &part2[slot * P2P];
                *(float4*)&p[oct * 8]     = make_float4(m1[0], m1[1], m1[2], m1[3]);
                *(float4*)&p[oct * 8 + 4] = make_float4(m1[4], m1[5], m1[6], m1[7]);
                if (oct < 5) {
                    *(float4*)&p[64 + oct * 8]     = make_float4(m2[0], m2[1], m2[2], m2[3]);
                    *(float4*)&p[64 + oct * 8 + 4] = make_float4(m2[4], m2[5], m2[6], m2[7]);
                }
            }
        }
        __syncthreads();   // B4

        // ---- reduce 16 k-pair partials -> msg_s row (bf16), waves 0,1
        if (w < 2) {
            int d = w * 64 + lane;
            if (d < 100) {
                float s = 0.0f;
                #pragma unroll
                for (int sl = 0; sl < 16; ++sl) s += part2[sl * P2P + d];
                msg_s[it * HP + d] = f2bf(s);
            }
        }
    }

    // ================= layer phase: x = relu([x,msg]@W2+b2) twice =================
    __syncthreads();   // all attn reads of h_s done; msg_s rows final after B_L1

    // W2 fragments + x-gather (emb[nodes]) -> h_s region
    bf16x8 Bf2[13];
    #pragma unroll
    for (int ks = 0; ks < 13; ++ks)
        Bf2[ks] = *(const bf16x8*)(W2t + n * 208 + ks * 16 + hi * 8);
    const float b2v = nok ? b2[n] : 0.0f;
    {
        int row = n0 + gk;
        int rc = row < N ? row : N - 1;
        const float4* xr = (const float4*)(emb + (size_t)nodes[rc] * 100);
        float4 x0 = xr[gj], x1 = xr[gj + 8], x2 = xr[gj + 16];
        float4 x3; const bool t24 = (gj == 0);
        if (t24) x3 = xr[24];
        *(uint2*)&h_s[gk * HP + gj * 4]        = make_uint2(pk2(x0.x, x0.y), pk2(x0.z, x0.w));
        *(uint2*)&h_s[gk * HP + (gj + 8) * 4]  = make_uint2(pk2(x1.x, x1.y), pk2(x1.z, x1.w));
        *(uint2*)&h_s[gk * HP + (gj + 16) * 4] = make_uint2(pk2(x2.x, x2.y), pk2(x2.z, x2.w));
        if (t24)
            *(uint2*)&h_s[gk * HP + 96]        = make_uint2(pk2(x3.x, x3.y), pk2(x3.z, x3.w));
    }
    __syncthreads();   // B_L1

    // A-frag address: k' blocks 0..12 -> h_s, 13..25 -> msg_s (ks=6 splits on hi)
    #define AFRAG(ks) (*(const bf16x8*)( \
        (ks) < 6  ? &h_s[col * HP + (ks) * 16 + hi * 8] : \
        (ks) == 6 ? (hi ? &msg_s[col * HP] : &h_s[col * HP + 96]) : \
                    &msg_s[col * HP + (ks) * 16 + hi * 8 - 104]))

    f32x16 acc;
    #pragma unroll
    for (int r = 0; r < 16; ++r) acc[r] = b2v;
    #pragma unroll
    for (int ks = 0; ks < 13; ++ks)
        acc = __builtin_amdgcn_mfma_f32_32x32x16_bf16(AFRAG(ks), Bf2[ks], acc, 0, 0, 0);
    __syncthreads();   // B_L2: pass-1 reads done
    if (nok) {
        #pragma unroll
        for (int r = 0; r < 16; ++r) {
            int m = (r & 3) + 8 * (r >> 2) + 4 * hi;
            h_s[m * HP + n] = f2bf(fmaxf(acc[r], 0.0f));
        }
    }
    __syncthreads();   // B_L3

    f32x16 acc2;
    #pragma unroll
    for (int r = 0; r < 16; ++r) acc2[r] = b2v;
    #pragma unroll
    for (int ks = 0; ks < 13; ++ks)
        acc2 = __builtin_amdgcn_mfma_f32_32x32x16_bf16(AFRAG(ks), Bf2[ks], acc2, 0, 0, 0);
    #undef AFRAG
    if (nok) {
        #pragma unroll
        for (int r = 0; r < 16; ++r) {
            int m = (r & 3) + 8 * (r >> 2) + 4 * hi;
            int row = n0 + m;
            if (row < N) out[(size_t)row * 100 + n] = fmaxf(acc2[r], 0.0f);
        }
    }
}

// ---------------- launch ----------------
extern "C" void kernel_launch(void* const* d_in, const int* in_sizes, int n_in,
                              void* d_out, int out_size, void* d_ws, size_t ws_size,
                              hipStream_t stream) {
    const int*   nodes = (const int*)d_in[0];
    const int*   nei   = (const int*)d_in[1];
    const float* wei   = (const float*)d_in[2];
    const float* s_vec = (const float*)d_in[3];
    const float* emb   = (const float*)d_in[4];
    const float* W1    = (const float*)d_in[5];
    const float* b1    = (const float*)d_in[6];
    const float* q1    = (const float*)d_in[7];
    const float* W2    = (const float*)d_in[8];
    const float* b2    = (const float*)d_in[9];
    float* out = (float*)d_out;
    const int N = in_sizes[0];

    unsigned short* W1t = (unsigned short*)d_ws;       // 128*128*2 = 32 KB
    unsigned short* W2t = W1t + 128 * 128;             // 128*208*2 = 52 KB

    prep_kernel<<<168, 256, 0, stream>>>(W1, W2, W1t, W2t);
    const int gB = (N + 31) / 32;
    fused_kernel<<<gB, 256, 0, stream>>>(nodes, nei, wei, s_vec, emb, W1, b1, q1,
                                         W1t, W2t, b2, out, N);
}